// Round 2
// baseline (247.732 us; speedup 1.0000x reference)
//
#include <hip/hip_runtime.h>
#include <math.h>

#define TAU_F 0.02f
#define NB 64
#define NQ 32
#define NS 256
#define ND 128
#define MAXT 12          // max 32-row tiles per doc (sum ceil(c_m/32)*32 <= 379)
#define PERMSTRIDE 384   // MAXT*32

typedef __bf16 bf16x8 __attribute__((ext_vector_type(8)));
typedef float f32x16 __attribute__((ext_vector_type(16)));

// workspace layout (bytes)
#define OFF_SIMOUT 0u          // 64*64*5*4 = 81920
#define OFF_RED    81920u      // done @+0, acc(float) @+64, bqcnt[8] @+128 (memset 256B)

__device__ inline bf16x8 cvt2(float4 a, float4 b) {
    bf16x8 o;
    o[0] = (__bf16)a.x; o[1] = (__bf16)a.y; o[2] = (__bf16)a.z; o[3] = (__bf16)a.w;
    o[4] = (__bf16)b.x; o[5] = (__bf16)b.y; o[6] = (__bf16)b.z; o[7] = (__bf16)b.w;
    return o;
}

// ---------------------------------------------------------------------------
// Single fused kernel. 512 blocks = 64 docs x 8 query-batches; 8 blocks of a
// doc share an XCD (demb L2 reuse). Main path unchanged from R1 (validated):
// ballot-based partition, demb->LDS staging w/ on-the-fly permute+bf16,
// double-buffered tile pipeline, 32x32x16 MFMA, per-wave epilogue.
// NEW: per-bq completion counter; last-arriving block of each bq computes the
// 8 row-losses (1 wave : 2 rows) and accumulates into acc; globally last loss
// block writes out[0]. Coherence: agent-scope atomic stores/loads on simout,
// device-scope atomics on counters (validated acc-readback pattern).
// ---------------------------------------------------------------------------
__global__ __launch_bounds__(256, 2) void
fused_kernel(const float* __restrict__ qemb, const float* __restrict__ demb,
             const int* __restrict__ mod, const int* __restrict__ qtypes,
             const int* __restrict__ qmask,
             float* __restrict__ simout, int* __restrict__ red,
             float* __restrict__ out) {
    int blk = blockIdx.x;              // 0..511
    int xcd = blk & 7;
    int idx = blk >> 3;                // 0..63
    int c   = xcd * 8 + (idx & 7);     // doc; 8 blocks per doc share an XCD
    int bq  = idx >> 3;                // 0..7 query-batch
    int tid = threadIdx.x;
    int lane = tid & 63, wv = tid >> 6;
    int li32 = lane & 31, kh = lane >> 5;
    int b0 = bq * 8 + wv * 2;          // this wave's 2 b's

    // ---- query fragments straight from qemb (issued early, L2/L3-hot) ----
    bf16x8 bfrag[2][8];
#pragma unroll
    for (int bi = 0; bi < 2; ++bi)
#pragma unroll
        for (int kc = 0; kc < 8; ++kc) {
            const float* src = qemb + ((size_t)(b0 + bi) * NQ + li32) * ND + kc * 16 + kh * 8;
            float4 a = *(const float4*)src;
            float4 b = *(const float4*)(src + 4);
            bfrag[bi][kc] = cvt2(a, b);
        }

    // ---- per-block doc partition via wave ballots (stable rank) ----
    __shared__ int sperm[PERMSTRIDE];
    __shared__ int wcnt[4][4];                    // [wave][modality-1]
    __shared__ int counts[5], firsts[5], offs[5], padded[5];
    __shared__ int stilemod[MAXT];
    __shared__ int sT;

    int m_tok = mod[c * NS + tid];
    int rank_w = 0;
#pragma unroll
    for (int m = 1; m <= 4; ++m) {
        unsigned long long bal = __ballot(m_tok == m);
        if (lane == 0) wcnt[wv][m - 1] = __popcll(bal);
        if (m_tok == m) rank_w = __popcll(bal & ((1ull << lane) - 1ull));
    }
    __syncthreads();
    if (tid == 0) {
        int pos = 0;
        for (int m = 1; m <= 4; ++m) {
            int cnt = wcnt[0][m-1] + wcnt[1][m-1] + wcnt[2][m-1] + wcnt[3][m-1];
            counts[m] = cnt;
            offs[m] = pos;
            int p = (cnt + 31) & ~31;
            padded[m] = p;
            for (int t = pos >> 5; t < (pos + p) >> 5; ++t) stilemod[t] = m;
            pos += p;
        }
        sT = pos >> 5;
    }
    __syncthreads();
    if (m_tok) {
        int rank = rank_w;
        for (int w = 0; w < wv; ++w) rank += wcnt[w][m_tok - 1];
        sperm[offs[m_tok] + rank] = tid;
        if (rank == 0) firsts[m_tok] = tid;   // stable => rank 0 is lowest tid
    }
    __syncthreads();
    if (tid < 4) {
        int m = tid + 1;
        for (int p = counts[m]; p < padded[m]; ++p) sperm[offs[m] + p] = firsts[m];
    }
    __syncthreads();
    int T = sT;

    // ---- doc tile staging: demb -> LDS fragments, permuted, bf16 ----
    __shared__ __bf16 sbuf[2][8 * 64 * 8];   // 2 x 8 KB tile buffers
    int row = tid & 31, chunk = tid >> 5;    // thread = (doc-row-in-tile, 16-float chunk)
    const float* drow_base = demb + (size_t)c * NS * ND + chunk * 16;

    // stage tile 0
    {
        int srow = sperm[row];
        const float4* s = (const float4*)(drow_base + (size_t)srow * ND);
        float4 a0 = s[0], a1 = s[1], a2 = s[2], a3 = s[3];
        *(bf16x8*)&sbuf[0][((chunk * 64) + row) * 8]      = cvt2(a0, a1);
        *(bf16x8*)&sbuf[0][((chunk * 64) + 32 + row) * 8] = cvt2(a2, a3);
    }
    __syncthreads();

    float vmax[2][4];
#pragma unroll
    for (int bi = 0; bi < 2; ++bi)
#pragma unroll
        for (int m = 0; m < 4; ++m) vmax[bi][m] = -1e30f;

    int cur = 0;
    for (int t = 0; t < T; ++t) {
        // prefetch next tile rows into VGPRs (latency hidden behind MFMA)
        float4 a0, a1, a2, a3;
        bool pf = (t + 1 < T);
        if (pf) {
            int srow = sperm[(t + 1) * 32 + row];
            const float4* s = (const float4*)(drow_base + (size_t)srow * ND);
            a0 = s[0]; a1 = s[1]; a2 = s[2]; a3 = s[3];
        }

        int tm = stilemod[t];   // wave-uniform LDS broadcast
        f32x16 acc0 = {0.f,0.f,0.f,0.f,0.f,0.f,0.f,0.f,0.f,0.f,0.f,0.f,0.f,0.f,0.f,0.f};
        f32x16 acc1 = acc0;
#pragma unroll
        for (int kc = 0; kc < 8; ++kc) {
            bf16x8 af = *(const bf16x8*)&sbuf[cur][(kc * 64 + lane) * 8];
            acc0 = __builtin_amdgcn_mfma_f32_32x32x16_bf16(af, bfrag[0][kc], acc0, 0, 0, 0);
            acc1 = __builtin_amdgcn_mfma_f32_32x32x16_bf16(af, bfrag[1][kc], acc1, 0, 0, 0);
        }
        float v0 = fmaxf(fmaxf(fmaxf(acc0[0], acc0[1]),  fmaxf(acc0[2],  acc0[3])),
                         fmaxf(fmaxf(acc0[4], acc0[5]),  fmaxf(acc0[6],  acc0[7])));
        v0 = fmaxf(v0,
             fmaxf(fmaxf(fmaxf(acc0[8], acc0[9]),  fmaxf(acc0[10], acc0[11])),
                   fmaxf(fmaxf(acc0[12], acc0[13]), fmaxf(acc0[14], acc0[15]))));
        float v1 = fmaxf(fmaxf(fmaxf(acc1[0], acc1[1]),  fmaxf(acc1[2],  acc1[3])),
                         fmaxf(fmaxf(acc1[4], acc1[5]),  fmaxf(acc1[6],  acc1[7])));
        v1 = fmaxf(v1,
             fmaxf(fmaxf(fmaxf(acc1[8], acc1[9]),  fmaxf(acc1[10], acc1[11])),
                   fmaxf(fmaxf(acc1[12], acc1[13]), fmaxf(acc1[14], acc1[15]))));
        v0 = fmaxf(v0, __shfl_xor(v0, 32, 64));
        v1 = fmaxf(v1, __shfl_xor(v1, 32, 64));
        switch (tm) {
        case 1:  vmax[0][0] = fmaxf(vmax[0][0], v0); vmax[1][0] = fmaxf(vmax[1][0], v1); break;
        case 2:  vmax[0][1] = fmaxf(vmax[0][1], v0); vmax[1][1] = fmaxf(vmax[1][1], v1); break;
        case 3:  vmax[0][2] = fmaxf(vmax[0][2], v0); vmax[1][2] = fmaxf(vmax[1][2], v1); break;
        default: vmax[0][3] = fmaxf(vmax[0][3], v0); vmax[1][3] = fmaxf(vmax[1][3], v1); break;
        }

        if (pf) {
            *(bf16x8*)&sbuf[cur ^ 1][((chunk * 64) + row) * 8]      = cvt2(a0, a1);
            *(bf16x8*)&sbuf[cur ^ 1][((chunk * 64) + 32 + row) * 8] = cvt2(a2, a3);
        }
        __syncthreads();
        cur ^= 1;
    }

    // ---- per-wave epilogue: agent-scope stores (cross-XCD visible) ----
    int q = lane & 31;
#pragma unroll
    for (int bi = 0; bi < 2; ++bi) {
        int b = b0 + bi;
        float m1 = vmax[bi][0], m2 = vmax[bi][1], m3 = vmax[bi][2], m4 = vmax[bi][3];
        float agg = fmaxf(fmaxf(m1, m2), fmaxf(m3, m4));
        float s0 = (qmask[b * NQ + q] != 0) ? agg : 0.f;
        float s1 = m1, s2 = m2, s3 = m3, s4 = m4;
#pragma unroll
        for (int off = 16; off >= 1; off >>= 1) {   // fold within 32-lane half
            s0 += __shfl_xor(s0, off, 64);
            s1 += __shfl_xor(s1, off, 64);
            s2 += __shfl_xor(s2, off, 64);
            s3 += __shfl_xor(s3, off, 64);
            s4 += __shfl_xor(s4, off, 64);
        }
        if (lane == 0) {
            float* o = simout + ((size_t)b * NB + c) * 5;   // UNNORMALIZED sums
            __hip_atomic_store(&o[0], s0, __ATOMIC_RELEASE, __HIP_MEMORY_SCOPE_AGENT);
            __hip_atomic_store(&o[1], s1, __ATOMIC_RELEASE, __HIP_MEMORY_SCOPE_AGENT);
            __hip_atomic_store(&o[2], s2, __ATOMIC_RELEASE, __HIP_MEMORY_SCOPE_AGENT);
            __hip_atomic_store(&o[3], s3, __ATOMIC_RELEASE, __HIP_MEMORY_SCOPE_AGENT);
            __hip_atomic_store(&o[4], s4, __ATOMIC_RELEASE, __HIP_MEMORY_SCOPE_AGENT);
        }
    }

    // ---- last-arriver loss: per-bq completion counter ----
    __shared__ int slast;
    __syncthreads();                     // drains the stores (vmcnt) before count
    if (tid == 0) {
        int old = atomicAdd(&red[32 + bq], 1);   // bqcnt[bq] @ byte 128
        slast = (old == NB - 1);
    }
    __syncthreads();
    if (!slast) return;

    // this block is the last of its bq: compute loss for rows bq*8..bq*8+7
    // wave wv handles rows 2wv and 2wv+1 (320 logits each, 5 per lane)
    float partial = 0.f;
#pragma unroll
    for (int h = 0; h < 2; ++h) {
        int b = bq * 8 + wv * 2 + h;
        int on = (lane < NQ) ? (qmask[b * NQ + lane] != 0) : 0;
        int cq = __popcll(__ballot(on));
        float scale = 1.0f / (TAU_F * (float)(cq > 0 ? cq : 1));
        const float* sv = simout + (size_t)b * (NB * 5);
        float v[5];
#pragma unroll
        for (int j = 0; j < 5; ++j)
            v[j] = __hip_atomic_load(&sv[lane + j * 64], __ATOMIC_ACQUIRE, __HIP_MEMORY_SCOPE_AGENT);
        int skip = b * 5;                 // the agg-sim diagonal slot (c==b, slot 0)
        float mx = -1e30f;
#pragma unroll
        for (int j = 0; j < 5; ++j) {
            int i = lane + j * 64;
            mx = fmaxf(mx, (i == skip) ? -1e30f : v[j] * scale);
        }
#pragma unroll
        for (int off = 32; off >= 1; off >>= 1) mx = fmaxf(mx, __shfl_xor(mx, off, 64));
        float sum = 0.f;
#pragma unroll
        for (int j = 0; j < 5; ++j) {
            int i = lane + j * 64;
            if (i != skip) sum += expf(v[j] * scale - mx);
        }
#pragma unroll
        for (int off = 32; off >= 1; off >>= 1) sum += __shfl_xor(sum, off, 64);
        int qt = qtypes[b];
        int ii = b * 5 + qt, jj = ii >> 6, ll = ii & 63;
        float vsel = (jj == 0) ? v[0] : (jj == 1) ? v[1] : (jj == 2) ? v[2]
                   : (jj == 3) ? v[3] : v[4];
        float pos = __shfl(vsel, ll, 64) * scale;
        if (lane == 0) partial += logf(sum) + mx - pos;
    }
    __shared__ float wred[4];
    if (lane == 0) wred[wv] = partial;
    __syncthreads();
    if (tid == 0) {
        float lr = (wred[0] + wred[1] + wred[2] + wred[3]) * (1.0f / NB);
        float* acc = (float*)red + 16;                   // acc @ byte 64
        float ret = atomicAdd(acc, lr);                  // device-coherent
        int bump = 1 + (ret > 1e37f ? 1 : 0);            // data-dep: order after acc add
        int old = atomicAdd(red, bump);                  // done counter @ byte 0
        if (old == 7) {                                  // 8 loss blocks total
            float v = atomicAdd(acc, 0.f);               // coherent read-back
            out[0] = v;
        }
    }
}

// ---------------------------------------------------------------------------
extern "C" void kernel_launch(void* const* d_in, const int* in_sizes, int n_in,
                              void* d_out, int out_size, void* d_ws, size_t ws_size,
                              hipStream_t stream) {
    const float* qemb   = (const float*)d_in[0];
    const float* demb   = (const float*)d_in[1];
    const int*   mod    = (const int*)d_in[2];
    const int*   qtypes = (const int*)d_in[3];
    const int*   qmask  = (const int*)d_in[4];

    char* ws = (char*)d_ws;
    float* simout = (float*)(ws + OFF_SIMOUT);
    int*   red    = (int*)(ws + OFF_RED);

    // zero the counters (done, acc, bqcnt[8]) — workspace is poisoned each iter
    hipMemsetAsync(red, 0, 256, stream);
    fused_kernel<<<512, 256, 0, stream>>>(qemb, demb, mod, qtypes, qmask,
                                          simout, red, (float*)d_out);
}

// Round 3
// 90.078 us; speedup vs baseline: 2.7502x; 2.7502x over previous
//
#include <hip/hip_runtime.h>
#include <math.h>

#define TAU_F 0.02f
#define NB 64
#define NQ 32
#define NS 256
#define ND 128
#define MAXT 12          // max 32-row tiles per doc (sum ceil(c_m/32)*32 <= 379)
#define PERMSTRIDE 384   // MAXT*32

typedef __bf16 bf16x8 __attribute__((ext_vector_type(8)));
typedef float f32x16 __attribute__((ext_vector_type(16)));

// workspace layout (bytes) — R0 layout (validated)
#define OFF_TILEMOD 0u          // 64*12*4 = 3072
#define OFF_TCOUNT  4096u       // 64*4
#define OFF_DFRAG   16384u      // 64*12*8*64*16 = 6291456
#define OFF_QFRAG   6307840u    // 64*8*64*16    = 524288
#define OFF_SIMOUT  6832128u    // 64*64*5*4     = 81920
#define OFF_RED     6914048u    // counter @ +0, acc(float) @ +64 bytes

__device__ inline bf16x8 cvt2(float4 a, float4 b) {
    bf16x8 o;
    o[0] = (__bf16)a.x; o[1] = (__bf16)a.y; o[2] = (__bf16)a.z; o[3] = (__bf16)a.w;
    o[4] = (__bf16)b.x; o[5] = (__bf16)b.y; o[6] = (__bf16)b.z; o[7] = (__bf16)b.w;
    return o;
}

// ---------------------------------------------------------------------------
// Kernel 1: prep + fragment swizzle. 64 blocks (one per doc; query fragments
// for b=blk folded in). Serial O(tid) rank loop replaced by ballot-based
// stable ranking (validated R1/R2). Output layouts identical to R0.
// ---------------------------------------------------------------------------
__global__ __launch_bounds__(256) void
prep_frag_kernel(const float* __restrict__ qemb, const float* __restrict__ demb,
                 const int* __restrict__ mod,
                 __bf16* __restrict__ qfrag, __bf16* __restrict__ dfrag,
                 int* __restrict__ tilemod_g, int* __restrict__ tcount_g,
                 int* __restrict__ red) {
    int c = blockIdx.x;                // doc, and query row b=c
    int tid = threadIdx.x;
    int lane = tid & 63, wv = tid >> 6;
    int li32 = lane & 31, kh = lane >> 5;

    if (c == 0 && tid == 0) { red[0] = 0; ((float*)red)[16] = 0.f; }

    // ---- query fragments for b = c: lane holds q col li32, k = kc*16+kh*8+j
#pragma unroll
    for (int i = 0; i < 2; ++i) {
        int kc = wv * 2 + i;               // 0..7
        int k0 = kc * 16 + kh * 8;
        const float* src = qemb + ((size_t)c * NQ + li32) * ND + k0;
        float4 a = *(const float4*)src;
        float4 b = *(const float4*)(src + 4);
        *(bf16x8*)(qfrag + (((size_t)c * 8 + kc) * 64 + lane) * 8) = cvt2(a, b);
    }

    // ---- doc partition via wave ballots (stable rank) ----
    __shared__ int sperm[PERMSTRIDE];
    __shared__ int wcnt[4][4];                    // [wave][modality-1]
    __shared__ int counts[5], firsts[5], offs[5], padded[5];
    __shared__ int stilemod[MAXT];
    __shared__ int sT;

    int m_tok = mod[c * NS + tid];
    int rank_w = 0;
#pragma unroll
    for (int m = 1; m <= 4; ++m) {
        unsigned long long bal = __ballot(m_tok == m);
        if (lane == 0) wcnt[wv][m - 1] = __popcll(bal);
        if (m_tok == m) rank_w = __popcll(bal & ((1ull << lane) - 1ull));
    }
    __syncthreads();
    if (tid == 0) {
        int pos = 0;
        for (int m = 1; m <= 4; ++m) {
            int cnt = wcnt[0][m-1] + wcnt[1][m-1] + wcnt[2][m-1] + wcnt[3][m-1];
            counts[m] = cnt;
            offs[m] = pos;
            int p = (cnt + 31) & ~31;
            padded[m] = p;
            for (int t = pos >> 5; t < (pos + p) >> 5; ++t) stilemod[t] = m;
            pos += p;
        }
        sT = pos >> 5;
        tcount_g[c] = pos >> 5;
    }
    __syncthreads();
    if (m_tok) {
        int rank = rank_w;
        for (int w = 0; w < wv; ++w) rank += wcnt[w][m_tok - 1];
        sperm[offs[m_tok] + rank] = tid;
        if (rank == 0) firsts[m_tok] = tid;   // stable => rank 0 is lowest tid
    }
    __syncthreads();
    if (tid < 4) {
        int m = tid + 1;
        for (int p = counts[m]; p < padded[m]; ++p) sperm[offs[m] + p] = firsts[m];
    }
    __syncthreads();
    int T = sT;
    if (tid < T) tilemod_g[c * MAXT + tid] = stilemod[tid];

    // ---- fragment swizzle: lane holds doc row li32 of tile t, k = kc*16+kh*8+j
    for (int kc = wv; kc < 8; kc += 4) {
        int k0 = kc * 16 + kh * 8;
        for (int t = 0; t < T; ++t) {
            int srow = sperm[t * 32 + li32];
            const float* src = demb + ((size_t)c * NS + srow) * ND + k0;
            float4 a = *(const float4*)src;
            float4 b = *(const float4*)(src + 4);
            *(bf16x8*)(dfrag + (((size_t)(c * MAXT + t) * 8 + kc) * 64 + lane) * 8) = cvt2(a, b);
        }
    }
}

// ---------------------------------------------------------------------------
// Kernel 2: main — byte-identical to R0 (validated, fastest measured).
// 512 blocks = 64 docs x 8 query-batches; all 8 blocks of a doc on one XCD.
// Each wave owns 2 b's end-to-end; doc tiles double-buffered through LDS with
// a global->VGPR prefetch pipeline (one barrier per tile).
// ---------------------------------------------------------------------------
__global__ __launch_bounds__(256, 2) void
main_kernel(const __bf16* __restrict__ dfrag, const __bf16* __restrict__ qfrag,
            const int* __restrict__ tilemod, const int* __restrict__ tcount,
            const int* __restrict__ qmask, float* __restrict__ simout) {
    int blk = blockIdx.x;              // 0..511
    int xcd = blk & 7;
    int idx = blk >> 3;                // 0..63
    int c   = xcd * 8 + (idx & 7);     // doc; 8 blocks per doc share an XCD
    int bq  = idx >> 3;                // 0..7 query-batch
    int tid = threadIdx.x;
    int lane = tid & 63, wv = tid >> 6;
    int b0 = bq * 8 + wv * 2;          // this wave's 2 b's

    // per-wave query fragments (distinct per wave)
    bf16x8 bfrag[2][8];
#pragma unroll
    for (int bi = 0; bi < 2; ++bi)
#pragma unroll
        for (int kc = 0; kc < 8; ++kc)
            bfrag[bi][kc] = *(const bf16x8*)(qfrag + (((size_t)(b0 + bi) * 8 + kc) * 64 + lane) * 8);

    __shared__ __bf16 sbuf[2][8 * 64 * 8];   // 2 x 8 KB tile buffers

    int T = tcount[c];
    const __bf16* dbase = dfrag + (size_t)c * MAXT * 4096;

    // stage tile 0 (coalesced: 256 threads x 2 x 16B)
    {
        const __bf16* src = dbase;
        *(bf16x8*)&sbuf[0][(size_t)tid * 8]          = *(const bf16x8*)(src + (size_t)tid * 8);
        *(bf16x8*)&sbuf[0][2048 + (size_t)tid * 8]   = *(const bf16x8*)(src + 2048 + (size_t)tid * 8);
    }
    __syncthreads();

    float vmax[2][4];
#pragma unroll
    for (int bi = 0; bi < 2; ++bi)
#pragma unroll
        for (int m = 0; m < 4; ++m) vmax[bi][m] = -1e30f;

    int cur = 0;
    for (int t = 0; t < T; ++t) {
        // prefetch next tile into VGPRs (latency hidden behind compute)
        bf16x8 p0, p1;
        bool pf = (t + 1 < T);
        if (pf) {
            const __bf16* src = dbase + (size_t)(t + 1) * 4096;
            p0 = *(const bf16x8*)(src + (size_t)tid * 8);
            p1 = *(const bf16x8*)(src + 2048 + (size_t)tid * 8);
        }

        int tm = tilemod[c * MAXT + t];   // wave-uniform
        f32x16 acc0 = {0.f,0.f,0.f,0.f,0.f,0.f,0.f,0.f,0.f,0.f,0.f,0.f,0.f,0.f,0.f,0.f};
        f32x16 acc1 = acc0;
#pragma unroll
        for (int kc = 0; kc < 8; ++kc) {
            bf16x8 af = *(const bf16x8*)&sbuf[cur][(kc * 64 + lane) * 8];
            acc0 = __builtin_amdgcn_mfma_f32_32x32x16_bf16(af, bfrag[0][kc], acc0, 0, 0, 0);
            acc1 = __builtin_amdgcn_mfma_f32_32x32x16_bf16(af, bfrag[1][kc], acc1, 0, 0, 0);
        }
        float v0 = acc0[0], v1 = acc1[0];
#pragma unroll
        for (int r = 1; r < 16; ++r) { v0 = fmaxf(v0, acc0[r]); v1 = fmaxf(v1, acc1[r]); }
        v0 = fmaxf(v0, __shfl_xor(v0, 32, 64));
        v1 = fmaxf(v1, __shfl_xor(v1, 32, 64));
        switch (tm) {
        case 1:  vmax[0][0] = fmaxf(vmax[0][0], v0); vmax[1][0] = fmaxf(vmax[1][0], v1); break;
        case 2:  vmax[0][1] = fmaxf(vmax[0][1], v0); vmax[1][1] = fmaxf(vmax[1][1], v1); break;
        case 3:  vmax[0][2] = fmaxf(vmax[0][2], v0); vmax[1][2] = fmaxf(vmax[1][2], v1); break;
        default: vmax[0][3] = fmaxf(vmax[0][3], v0); vmax[1][3] = fmaxf(vmax[1][3], v1); break;
        }

        if (pf) {
            *(bf16x8*)&sbuf[cur ^ 1][(size_t)tid * 8]        = p0;
            *(bf16x8*)&sbuf[cur ^ 1][2048 + (size_t)tid * 8] = p1;
        }
        __syncthreads();
        cur ^= 1;
    }

    // per-wave epilogue: no cross-wave reduction needed (wave owns its 2 b's)
    int q = lane & 31;
#pragma unroll
    for (int bi = 0; bi < 2; ++bi) {
        int b = b0 + bi;
        float m1 = vmax[bi][0], m2 = vmax[bi][1], m3 = vmax[bi][2], m4 = vmax[bi][3];
        float agg = fmaxf(fmaxf(m1, m2), fmaxf(m3, m4));
        float s0 = (qmask[b * NQ + q] != 0) ? agg : 0.f;
        float s1 = m1, s2 = m2, s3 = m3, s4 = m4;
#pragma unroll
        for (int off = 16; off >= 1; off >>= 1) {   // fold within 32-lane half
            s0 += __shfl_xor(s0, off, 64);
            s1 += __shfl_xor(s1, off, 64);
            s2 += __shfl_xor(s2, off, 64);
            s3 += __shfl_xor(s3, off, 64);
            s4 += __shfl_xor(s4, off, 64);
        }
        if (lane == 0) {
            float* o = simout + ((size_t)b * NB + c) * 5;   // UNNORMALIZED sums
            o[0] = s0; o[1] = s1; o[2] = s2; o[3] = s3; o[4] = s4;
        }
    }
}

// ---------------------------------------------------------------------------
// Kernel 3: loss, 64 blocks (one per row) — byte-identical to R0 (validated).
// ---------------------------------------------------------------------------
__global__ __launch_bounds__(256) void
loss_kernel(const float* __restrict__ simout, const int* __restrict__ qtypes,
            const int* __restrict__ qmask, int* __restrict__ red,
            float* __restrict__ out) {
    int r = blockIdx.x;
    int tid = threadIdx.x;
    int lane = tid & 63, wv = tid >> 6;

    __shared__ float sv[320];
    for (int i = tid; i < 320; i += 256) sv[i] = simout[(size_t)r * 320 + i];

    __shared__ int scnt;
    if (wv == 0) {
        int on = (lane < NQ) ? (qmask[r * NQ + lane] != 0) : 0;
        unsigned long long bal = __ballot(on);
        if (lane == 0) scnt = __popcll(bal);
    }
    __syncthreads();
    int cq = scnt;
    float scale = 1.0f / (TAU_F * (float)(cq > 0 ? cq : 1));
    int skip = r * 5;                      // the agg-sim diagonal slot

    __shared__ float wred[4];
    float mx = -1e30f;
    for (int i = tid; i < 320; i += 256)
        if (i != skip) mx = fmaxf(mx, sv[i] * scale);
#pragma unroll
    for (int off = 32; off >= 1; off >>= 1) mx = fmaxf(mx, __shfl_xor(mx, off, 64));
    if (lane == 0) wred[wv] = mx;
    __syncthreads();
    mx = fmaxf(fmaxf(wred[0], wred[1]), fmaxf(wred[2], wred[3]));

    float sum = 0.f;
    for (int i = tid; i < 320; i += 256)
        if (i != skip) sum += expf(sv[i] * scale - mx);
#pragma unroll
    for (int off = 32; off >= 1; off >>= 1) sum += __shfl_xor(sum, off, 64);
    __syncthreads();
    if (lane == 0) wred[wv] = sum;
    __syncthreads();

    if (tid == 0) {
        float tot = wred[0] + wred[1] + wred[2] + wred[3];
        float pos = sv[r * 5 + qtypes[r]] * scale;
        float lr = (logf(tot) + mx - pos) * (1.0f / NB);
        float* acc = (float*)red + 16;
        float ret = atomicAdd(acc, lr);                  // device-coherent
        int bump = 1 + (ret > 1e37f ? 1 : 0);            // data-dep: wait ret
        int old = atomicAdd(red, bump);
        if (old == NB - 1) {
            float v = atomicAdd(acc, 0.f);               // coherent read-back
            out[0] = v;
        }
    }
}

// ---------------------------------------------------------------------------
extern "C" void kernel_launch(void* const* d_in, const int* in_sizes, int n_in,
                              void* d_out, int out_size, void* d_ws, size_t ws_size,
                              hipStream_t stream) {
    const float* qemb   = (const float*)d_in[0];
    const float* demb   = (const float*)d_in[1];
    const int*   mod    = (const int*)d_in[2];
    const int*   qtypes = (const int*)d_in[3];
    const int*   qmask  = (const int*)d_in[4];

    char* ws = (char*)d_ws;
    int*    tilemod = (int*)(ws + OFF_TILEMOD);
    int*    tcount  = (int*)(ws + OFF_TCOUNT);
    __bf16* dfrag   = (__bf16*)(ws + OFF_DFRAG);
    __bf16* qfrag   = (__bf16*)(ws + OFF_QFRAG);
    float*  simout  = (float*)(ws + OFF_SIMOUT);
    int*    red     = (int*)(ws + OFF_RED);

    prep_frag_kernel<<<NB, 256, 0, stream>>>(qemb, demb, mod, qfrag, dfrag,
                                             tilemod, tcount, red);
    main_kernel<<<512, 256, 0, stream>>>(dfrag, qfrag, tilemod, tcount, qmask, simout);
    loss_kernel<<<NB, 256, 0, stream>>>(simout, qtypes, qmask, red, (float*)d_out);
}